// Round 9
// baseline (150.750 us; speedup 1.0000x reference)
//
#include <hip/hip_runtime.h>
#include <math.h>

#define DD 4096
#define HH 1024
#define BB 256
#define SS 256

typedef unsigned long long u64;
typedef __attribute__((ext_vector_type(4))) short sv4;
typedef __attribute__((ext_vector_type(8))) short sv8;
typedef __attribute__((ext_vector_type(4))) float f32x4;

// ------------------------------------------------------------ bf16 split ----
__device__ __forceinline__ unsigned short f2bf(float x) {
    union { float f; unsigned u; } c; c.f = x;
    unsigned r = c.u + 0x7FFFu + ((c.u >> 16) & 1u);
    return (unsigned short)(r >> 16);
}
__device__ __forceinline__ float bf2f(unsigned short h) {
    union { unsigned u; float f; } c; c.u = ((unsigned)h) << 16;
    return c.f;
}
// x = hi + lo with hi,lo bf16 (RNE twice) -> ~2^-16 relative residual
__device__ __forceinline__ void split4(const float4& v, sv4& h, sv4& l) {
    unsigned short hx = f2bf(v.x), hy = f2bf(v.y), hz = f2bf(v.z), hw = f2bf(v.w);
    h.x = (short)hx; h.y = (short)hy; h.z = (short)hz; h.w = (short)hw;
    l.x = (short)f2bf(v.x - bf2f(hx)); l.y = (short)f2bf(v.y - bf2f(hy));
    l.z = (short)f2bf(v.z - bf2f(hz)); l.w = (short)f2bf(v.w - bf2f(hw));
}
// two float4 (16 consecutive floats) -> sv8 hi + sv8 lo
__device__ __forceinline__ void split8(const float4& a, const float4& b,
                                       sv8& h, sv8& l) {
    sv4 h0, l0, h1, l1;
    split4(a, h0, l0);
    split4(b, h1, l1);
    h.s0 = h0.x; h.s1 = h0.y; h.s2 = h0.z; h.s3 = h0.w;
    h.s4 = h1.x; h.s5 = h1.y; h.s6 = h1.z; h.s7 = h1.w;
    l.s0 = l0.x; l.s1 = l0.y; l.s2 = l0.z; l.s3 = l0.w;
    l.s4 = l1.x; l.s5 = l1.y; l.s6 = l1.z; l.s7 = l1.w;
}

// ------------------------------------------------------------------ prep ----
// 257 blocks x 256 thr. Compact active ids (stable), bitonic-sort ascending.
// Sorted ascending order => concurrent doc-blocks sweep embed together
// (LLC reuse of the ~1.6x duplicated rows). Sum-reorder numerically safe.
__global__ __launch_bounds__(256) void prep_kernel(
        const int* __restrict__ ids, const int* __restrict__ mask,
        const int* __restrict__ qids, const int* __restrict__ qmask,
        int* __restrict__ SortedOff, int* __restrict__ Count) {
    __shared__ int s_key[256];
    __shared__ int wofs[4];
    int b = blockIdx.x, t = threadIdx.x;
    const int* I = (b < BB) ? ids  + b * SS : qids;
    const int* M = (b < BB) ? mask + b * SS : qmask;
    int id = I[t], m = M[t];
    u64 bal = __ballot(m != 0);
    int lane = t & 63, w = t >> 6;
    if (lane == 0) wofs[w] = __popcll(bal);
    s_key[t] = 0x7FFFFFFF;
    __syncthreads();
    int off = 0;
    #pragma unroll
    for (int i = 0; i < 4; ++i) if (i < w) off += wofs[i];
    int total = wofs[0] + wofs[1] + wofs[2] + wofs[3];
    if (m) s_key[off + __popcll(bal & ((1ull << lane) - 1ull))] = id;
    __syncthreads();
    for (int k = 2; k <= 256; k <<= 1) {
        for (int j = k >> 1; j > 0; j >>= 1) {
            int p = t ^ j;
            int a = s_key[t], c = s_key[p];
            bool dir = ((t & k) == 0);
            bool keepMin = ((t < p) == dir);
            int nv = keepMin ? (a < c ? a : c) : (a > c ? a : c);
            __syncthreads();
            s_key[t] = nv;
            __syncthreads();
        }
    }
    SortedOff[b * 256 + t] = (t < total) ? s_key[t] * DD : 0;
    if (t == 0) Count[b] = total;
}

// ------------------------------------------------------------------ pool ----
// grid 4112 = 257 docs x 16 slices, 64 thr. Slice = 256 cols. 16 gather rows
// in flight (16 float4 = 64 VGPR); ~16 blocks/CU smooths tail.
__global__ __launch_bounds__(64) void pool_kernel(
        const int* __restrict__ SortedOff, const int* __restrict__ Count,
        const float* __restrict__ embed, float* __restrict__ Pooled) {
    __shared__ int s_off[256];
    int bid = blockIdx.x, t = threadIdx.x;
    int doc = bid >> 4, slice = bid & 15;
    int total = Count[doc];
    #pragma unroll
    for (int i = 0; i < 4; ++i) s_off[t + i * 64] = SortedOff[doc * 256 + t + i * 64];
    __syncthreads();
    float inv = 1.0f / ((float)total + 1e-9f);
    int col = (slice << 8) + (t << 2);
    const float* eb = embed + col;
    float ax = 0.f, ay = 0.f, az = 0.f, aw = 0.f;
    int j = 0;
    for (; j + 16 <= total; j += 16) {
        float4 r[16];
        #pragma unroll
        for (int i = 0; i < 16; ++i) r[i] = *(const float4*)(eb + s_off[j + i]);
        #pragma unroll
        for (int i = 0; i < 16; ++i) {
            ax += r[i].x; ay += r[i].y; az += r[i].z; aw += r[i].w;
        }
    }
    if (j + 8 <= total) {
        float4 r[8];
        #pragma unroll
        for (int i = 0; i < 8; ++i) r[i] = *(const float4*)(eb + s_off[j + i]);
        #pragma unroll
        for (int i = 0; i < 8; ++i) {
            ax += r[i].x; ay += r[i].y; az += r[i].z; aw += r[i].w;
        }
        j += 8;
    }
    for (; j < total; ++j) {
        const float4 r0 = *(const float4*)(eb + s_off[j]);
        ax += r0.x; ay += r0.y; az += r0.z; aw += r0.w;
    }
    *(float4*)(Pooled + (size_t)doc * DD + col) =
        make_float4(ax * inv, ay * inv, az * inv, aw * inv);
}

// -------------------------------------------------------------- LN+split ----
// 257 blocks x 256 thr: LayerNorm Pooled row; docs -> split bf16 Xh/Xl,
// query (b==256) -> fp32 Xq.
__global__ __launch_bounds__(256) void ln_split_kernel(
        const float* __restrict__ Pooled, const float* __restrict__ g,
        const float* __restrict__ bb, short* __restrict__ Xh,
        short* __restrict__ Xl, float* __restrict__ Xq) {
    __shared__ float lds4[4];
    int b = blockIdx.x, t = threadIdx.x;
    const float* row = Pooled + (size_t)b * DD;
    float4 v[4];
    float s = 0.f;
    #pragma unroll
    for (int i = 0; i < 4; ++i) {
        v[i] = *(const float4*)(row + (t << 2) + (i << 10));
        s += (v[i].x + v[i].y) + (v[i].z + v[i].w);
    }
    #pragma unroll
    for (int o = 32; o; o >>= 1) s += __shfl_down(s, o);
    int lane = t & 63, w = t >> 6;
    if (lane == 0) lds4[w] = s;
    __syncthreads();
    float mu = (lds4[0] + lds4[1] + lds4[2] + lds4[3]) * (1.0f / DD);
    float q = 0.f;
    #pragma unroll
    for (int i = 0; i < 4; ++i) {
        float dx = v[i].x - mu, dy = v[i].y - mu, dz = v[i].z - mu, dw = v[i].w - mu;
        q += (dx * dx + dy * dy) + (dz * dz + dw * dw);
    }
    __syncthreads();
    #pragma unroll
    for (int o = 32; o; o >>= 1) q += __shfl_down(q, o);
    if (lane == 0) lds4[w] = q;
    __syncthreads();
    float var = (lds4[0] + lds4[1] + lds4[2] + lds4[3]) * (1.0f / DD);
    float sc = 1.0f / sqrtf(var + 1e-5f);
    #pragma unroll
    for (int i = 0; i < 4; ++i) {
        int col = (t << 2) + (i << 10);
        float4 gg = *(const float4*)(g + col);
        float4 bv = *(const float4*)(bb + col);
        float4 o4;
        o4.x = (v[i].x - mu) * sc * gg.x + bv.x;
        o4.y = (v[i].y - mu) * sc * gg.y + bv.y;
        o4.z = (v[i].z - mu) * sc * gg.z + bv.z;
        o4.w = (v[i].w - mu) * sc * gg.w + bv.w;
        if (b < BB) {
            sv4 h, l; split4(o4, h, l);
            *(sv4*)(Xh + (size_t)b * DD + col) = h;
            *(sv4*)(Xl + (size_t)b * DD + col) = l;
        } else {
            *(float4*)(Xq + col) = o4;
        }
    }
}

// ------------------------------------------------- split-bf16 MFMA GEMM -----
// BM=BN=128, BK=32, 256 thr (4 waves 2x2), wave tile 64x64 = 4x4 16x16 frags.
// C = Ah*Bh + Ah*Bl + Al*Bh (fp32 acc); B = fp32 weights split in-staging.
// C/D layout (m89): col = lane&15, row = (lane>>4)*4 + reg.
template <bool CONTRIB>
__device__ void gemm_mfma(
        const short* __restrict__ Ah, const short* __restrict__ Al,
        const float* __restrict__ Wf,
        int ldK, int m0, int n0, int kBase, int Kc, int N,
        float* __restrict__ Pout,
        const float* __restrict__ Qv, float* __restrict__ Contrib, int slot) {
    __shared__ short sAh[128 * 40] __attribute__((aligned(16)));
    __shared__ short sAl[128 * 40] __attribute__((aligned(16)));
    __shared__ short sBh[128 * 40] __attribute__((aligned(16)));
    __shared__ short sBl[128 * 40] __attribute__((aligned(16)));
    int tid = threadIdx.x;
    int lane = tid & 63, wv = tid >> 6;
    int wr = wv >> 1, wc = wv & 1;
    int l15 = lane & 15, grp = lane >> 4, lk = grp << 3;
    int srow = tid >> 1, soff = (tid & 1) << 4;   // 2 thr/row, 16 elems each
    f32x4 zero = {0.f, 0.f, 0.f, 0.f};
    f32x4 acc[4][4];
    #pragma unroll
    for (int i = 0; i < 4; ++i)
        #pragma unroll
        for (int j = 0; j < 4; ++j) acc[i][j] = zero;

    for (int k0 = 0; k0 < Kc; k0 += 32) {
        int gk = kBase + k0;
        size_t ga = (size_t)(m0 + srow) * ldK + gk + soff;
        sv8 vah0 = *(const sv8*)(Ah + ga);
        sv8 vah1 = *(const sv8*)(Ah + ga + 8);
        sv8 val0 = *(const sv8*)(Al + ga);
        sv8 val1 = *(const sv8*)(Al + ga + 8);
        const float* wp = Wf + (size_t)(n0 + srow) * ldK + gk + soff;
        float4 w0 = *(const float4*)(wp);
        float4 w1 = *(const float4*)(wp + 4);
        float4 w2 = *(const float4*)(wp + 8);
        float4 w3 = *(const float4*)(wp + 12);
        sv8 bh0, bl0, bh1, bl1;
        split8(w0, w1, bh0, bl0);
        split8(w2, w3, bh1, bl1);
        __syncthreads();
        int so = srow * 40 + soff;
        *(sv8*)(sAh + so) = vah0; *(sv8*)(sAh + so + 8) = vah1;
        *(sv8*)(sAl + so) = val0; *(sv8*)(sAl + so + 8) = val1;
        *(sv8*)(sBh + so) = bh0;  *(sv8*)(sBh + so + 8) = bh1;
        *(sv8*)(sBl + so) = bl0;  *(sv8*)(sBl + so + 8) = bl1;
        __syncthreads();
        sv8 fah[4], fal[4], fbh[4], fbl[4];
        #pragma unroll
        for (int i = 0; i < 4; ++i) {
            int ra = (wr * 64 + i * 16 + l15) * 40 + lk;
            int rb = (wc * 64 + i * 16 + l15) * 40 + lk;
            fah[i] = *(const sv8*)(sAh + ra);
            fal[i] = *(const sv8*)(sAl + ra);
            fbh[i] = *(const sv8*)(sBh + rb);
            fbl[i] = *(const sv8*)(sBl + rb);
        }
        #pragma unroll
        for (int i = 0; i < 4; ++i)
            #pragma unroll
            for (int j = 0; j < 4; ++j) {
                acc[i][j] = __builtin_amdgcn_mfma_f32_16x16x32_bf16(fah[i], fbh[j], acc[i][j], 0, 0, 0);
                acc[i][j] = __builtin_amdgcn_mfma_f32_16x16x32_bf16(fah[i], fbl[j], acc[i][j], 0, 0, 0);
                acc[i][j] = __builtin_amdgcn_mfma_f32_16x16x32_bf16(fal[i], fbh[j], acc[i][j], 0, 0, 0);
            }
    }

    if (CONTRIB) {
        float qv[4];
        #pragma unroll
        for (int j = 0; j < 4; ++j) qv[j] = Qv[n0 + wc * 64 + j * 16 + l15];
        #pragma unroll
        for (int i = 0; i < 4; ++i)
            #pragma unroll
            for (int r = 0; r < 4; ++r) {
                float s = acc[i][0][r] * qv[0] + acc[i][1][r] * qv[1]
                        + acc[i][2][r] * qv[2] + acc[i][3][r] * qv[3];
                s += __shfl_xor(s, 1); s += __shfl_xor(s, 2);
                s += __shfl_xor(s, 4); s += __shfl_xor(s, 8);
                if (l15 == 0) {
                    int row = m0 + wr * 64 + i * 16 + grp * 4 + r;
                    Contrib[(size_t)row * 256 + slot * 2 + wc] = s;
                }
            }
    } else {
        #pragma unroll
        for (int i = 0; i < 4; ++i)
            #pragma unroll
            for (int r = 0; r < 4; ++r) {
                int row = m0 + wr * 64 + i * 16 + grp * 4 + r;
                #pragma unroll
                for (int j = 0; j < 4; ++j)
                    Pout[(size_t)row * N + n0 + wc * 64 + j * 16 + l15] = acc[i][j][r];
            }
    }
}

// --------------------------------------------------------------- layer 1 ----
// bid<128: split-K=8 MFMA GEMM X @ kW1^T -> P1[z] (Kc=512);
// bid in [128,384): query GEMV1 (256 blocks, 4 rows each).
__global__ __launch_bounds__(256) void layer1_kernel(
        const short* __restrict__ Xh, const short* __restrict__ Xl,
        const float* __restrict__ kW1,
        float* __restrict__ P1, const float* __restrict__ Xq,
        const float* __restrict__ qW1, const float* __restrict__ qb1,
        float* __restrict__ H1q) {
    int bid = blockIdx.x;
    if (bid < 128) {
        int z = bid & 7, nb = (bid >> 3) & 7, mb = bid >> 6;
        gemm_mfma<false>(Xh, Xl, kW1, DD, mb * 128, nb * 128, z * 512, 512,
                         HH, P1 + (size_t)z * BB * HH, nullptr, nullptr, 0);
    } else {
        int i = bid - 128, wv = threadIdx.x >> 6, lane = threadIdx.x & 63;
        int n = (i << 2) + wv;
        const float* wrow = qW1 + (size_t)n * DD;
        float s = 0.f;
        #pragma unroll
        for (int jj = 0; jj < 16; ++jj) {
            int k = jj * 256 + (lane << 2);
            float4 a = *(const float4*)(Xq + k);
            float4 ww = *(const float4*)(wrow + k);
            s += (a.x * ww.x + a.y * ww.y) + (a.z * ww.z + a.w * ww.w);
        }
        #pragma unroll
        for (int o = 32; o; o >>= 1) s += __shfl_down(s, o);
        if (lane == 0) H1q[n] = fmaxf(s + qb1[n], 0.f);
    }
}

// ------------------------------------------------------ reduce1 + GEMV2 -----
// bid<256: H1[row] = relu(sum_z P1z + kb1) -> split bf16; bid>=256: Qv GEMV.
__global__ __launch_bounds__(256) void reduce1_kernel(
        const float* __restrict__ P1, const float* __restrict__ kb1,
        short* __restrict__ H1h, short* __restrict__ H1l,
        const float* __restrict__ H1q, const float* __restrict__ qW2,
        const float* __restrict__ qb2, float* __restrict__ Qv) {
    int bid = blockIdx.x, t = threadIdx.x;
    if (bid < 256) {
        int col = t << 2;
        const float* base = P1 + (size_t)bid * HH + col;
        float4 s = *(const float4*)(kb1 + col);
        #pragma unroll
        for (int z = 0; z < 8; ++z) {
            float4 p = *(const float4*)(base + (size_t)z * BB * HH);
            s.x += p.x; s.y += p.y; s.z += p.z; s.w += p.w;
        }
        s.x = fmaxf(s.x, 0.f); s.y = fmaxf(s.y, 0.f);
        s.z = fmaxf(s.z, 0.f); s.w = fmaxf(s.w, 0.f);
        sv4 h, l; split4(s, h, l);
        size_t o = (size_t)bid * HH + col;
        *(sv4*)(H1h + o) = h;
        *(sv4*)(H1l + o) = l;
    } else {
        int i = bid - 256, wv = t >> 6, lane = t & 63;
        int n = (i << 2) + wv;
        const float* wrow = qW2 + (size_t)n * HH;
        float s = 0.f;
        #pragma unroll
        for (int jj = 0; jj < 4; ++jj) {
            int k = jj * 256 + (lane << 2);
            float4 a = *(const float4*)(H1q + k);
            float4 ww = *(const float4*)(wrow + k);
            s += (a.x * ww.x + a.y * ww.y) + (a.z * ww.z + a.w * ww.w);
        }
        #pragma unroll
        for (int o = 32; o; o >>= 1) s += __shfl_down(s, o);
        if (lane == 0) Qv[n] = s + qb2[n];
    }
}

// --------------------------------------------------------------- layer 2 ----
// split-K=16 MFMA GEMM H1 @ kW2^T, tile reduced against Qv -> Contrib.
__global__ __launch_bounds__(256) void layer2_kernel(
        const short* __restrict__ H1h, const short* __restrict__ H1l,
        const float* __restrict__ kW2,
        const float* __restrict__ Qv, float* __restrict__ Contrib) {
    int bid = blockIdx.x;
    int z = bid & 15, nb = (bid >> 4) & 7, mb = bid >> 7;
    gemm_mfma<true>(H1h, H1l, kW2, HH, mb * 128, nb * 128, z * 64, 64,
                    HH, nullptr, Qv, Contrib, z * 8 + nb);
}

// ------------------------------------------------- final: scores + topk -----
__global__ __launch_bounds__(1024) void final_kernel(
        const float* __restrict__ Contrib, const float* __restrict__ kb2,
        const float* __restrict__ Qv, const int* __restrict__ kptr,
        float* __restrict__ out) {
    __shared__ float red[16];
    __shared__ float ss[BB];
    __shared__ float rv[16];
    __shared__ int   ri[16];
    __shared__ float s_bq;
    int t = threadIdx.x, lane = t & 63, w = t >> 6;
    float v = kb2[t] * Qv[t];
    #pragma unroll
    for (int o = 32; o; o >>= 1) v += __shfl_down(v, o);
    if (lane == 0) red[w] = v;
    __syncthreads();
    if (t == 0) {
        float b = 0.f;
        #pragma unroll
        for (int i = 0; i < 16; ++i) b += red[i];
        s_bq = b;
    }
    __syncthreads();
    if (t < BB) {
        const float* c = Contrib + (size_t)t * 256;
        float sx = 0.f, sy = 0.f, sz = 0.f, sw = 0.f;
        for (int j = 0; j < 256; j += 4) {
            float4 e = *(const float4*)(c + j);
            sx += e.x; sy += e.y; sz += e.z; sw += e.w;
        }
        float lg = s_bq + ((sx + sy) + (sz + sw));
        ss[t] = 1.0f / (1.0f + expf(-lg));
    }
    __syncthreads();
    int k = kptr[0];
    if (k > BB) k = BB;
    for (int i = 0; i < k; ++i) {
        float vv = (t < BB) ? ss[t] : -3.3e38f;
        int vi = t;
        #pragma unroll
        for (int o = 32; o; o >>= 1) {
            float ov = __shfl_down(vv, o);
            int   oi = __shfl_down(vi, o);
            if (ov > vv || (ov == vv && oi < vi)) { vv = ov; vi = oi; }
        }
        if (lane == 0) { rv[w] = vv; ri[w] = vi; }
        __syncthreads();
        if (t == 0) {
            float bv = rv[0]; int bi = ri[0];
            #pragma unroll
            for (int j = 1; j < 16; ++j)
                if (rv[j] > bv || (rv[j] == bv && ri[j] < bi)) { bv = rv[j]; bi = ri[j]; }
            out[i]     = bv;
            out[k + i] = (float)bi;
            ss[bi] = -3.0e38f;
        }
        __syncthreads();
    }
}

// ---------------------------------------------------------------- launch ----
extern "C" void kernel_launch(void* const* d_in, const int* in_sizes, int n_in,
                              void* d_out, int out_size, void* d_ws, size_t ws_size,
                              hipStream_t stream) {
    const int*   input_ids  = (const int*)d_in[0];
    const int*   attn_mask  = (const int*)d_in[1];
    const int*   query_ids  = (const int*)d_in[2];
    const int*   query_mask = (const int*)d_in[3];
    const float* embed      = (const float*)d_in[4];
    const float* ln_g       = (const float*)d_in[5];
    const float* ln_b       = (const float*)d_in[6];
    const float* kW1        = (const float*)d_in[7];
    const float* kb1        = (const float*)d_in[8];
    const float* kW2        = (const float*)d_in[9];
    const float* kb2        = (const float*)d_in[10];
    const float* qW1        = (const float*)d_in[11];
    const float* qb1        = (const float*)d_in[12];
    const float* qW2        = (const float*)d_in[13];
    const float* qb2        = (const float*)d_in[14];
    const int*   kptr       = (const int*)d_in[15];

    char* p = (char*)d_ws;
    auto carve = [&](size_t bytes) {
        char* r = p;
        p += (bytes + 255) & ~(size_t)255;
        return r;
    };
    int*   SortedOff = (int*)carve((size_t)257 * 256 * 4);
    int*   Count     = (int*)carve((size_t)257 * 4);
    float* Pooled    = (float*)carve((size_t)257 * DD * 4);
    float* Xq        = (float*)carve((size_t)DD * 4);
    short* Xh        = (short*)carve((size_t)BB * DD * 2);
    short* Xl        = (short*)carve((size_t)BB * DD * 2);
    float* P1        = (float*)carve((size_t)8 * BB * HH * 4);
    float* H1q       = (float*)carve((size_t)HH * 4);
    short* H1h       = (short*)carve((size_t)BB * HH * 2);
    short* H1l       = (short*)carve((size_t)BB * HH * 2);
    float* Qv        = (float*)carve((size_t)HH * 4);
    float* Contrib   = (float*)carve((size_t)BB * 256 * 4);

    prep_kernel<<<257, 256, 0, stream>>>(input_ids, attn_mask, query_ids,
                                         query_mask, SortedOff, Count);
    pool_kernel<<<4112, 64, 0, stream>>>(SortedOff, Count, embed, Pooled);
    ln_split_kernel<<<257, 256, 0, stream>>>(Pooled, ln_g, ln_b, Xh, Xl, Xq);
    layer1_kernel<<<384, 256, 0, stream>>>(Xh, Xl, kW1, P1, Xq, qW1, qb1, H1q);
    reduce1_kernel<<<512, 256, 0, stream>>>(P1, kb1, H1h, H1l, H1q, qW2, qb2, Qv);
    layer2_kernel<<<256, 256, 0, stream>>>(H1h, H1l, kW2, Qv, Contrib);
    final_kernel<<<1, 1024, 0, stream>>>(Contrib, kb2, Qv, kptr, (float*)d_out);
}

// Round 10
// 148.224 us; speedup vs baseline: 1.0170x; 1.0170x over previous
//
#include <hip/hip_runtime.h>
#include <math.h>

#define DD 4096
#define HH 1024
#define BB 256
#define SS 256

typedef unsigned long long u64;
typedef __attribute__((ext_vector_type(4))) short sv4;
typedef __attribute__((ext_vector_type(8))) short sv8;
typedef __attribute__((ext_vector_type(4))) float f32x4;

// ------------------------------------------------------------ bf16 split ----
__device__ __forceinline__ unsigned short f2bf(float x) {
    union { float f; unsigned u; } c; c.f = x;
    unsigned r = c.u + 0x7FFFu + ((c.u >> 16) & 1u);
    return (unsigned short)(r >> 16);
}
__device__ __forceinline__ float bf2f(unsigned short h) {
    union { unsigned u; float f; } c; c.u = ((unsigned)h) << 16;
    return c.f;
}
// x = hi + lo with hi,lo bf16 (RNE twice) -> ~2^-16 relative residual
__device__ __forceinline__ void split4(const float4& v, sv4& h, sv4& l) {
    unsigned short hx = f2bf(v.x), hy = f2bf(v.y), hz = f2bf(v.z), hw = f2bf(v.w);
    h.x = (short)hx; h.y = (short)hy; h.z = (short)hz; h.w = (short)hw;
    l.x = (short)f2bf(v.x - bf2f(hx)); l.y = (short)f2bf(v.y - bf2f(hy));
    l.z = (short)f2bf(v.z - bf2f(hz)); l.w = (short)f2bf(v.w - bf2f(hw));
}
// two float4 (16 consecutive floats) -> sv8 hi + sv8 lo
__device__ __forceinline__ void split8(const float4& a, const float4& b,
                                       sv8& h, sv8& l) {
    sv4 h0, l0, h1, l1;
    split4(a, h0, l0);
    split4(b, h1, l1);
    h.s0 = h0.x; h.s1 = h0.y; h.s2 = h0.z; h.s3 = h0.w;
    h.s4 = h1.x; h.s5 = h1.y; h.s6 = h1.z; h.s7 = h1.w;
    l.s0 = l0.x; l.s1 = l0.y; l.s2 = l0.z; l.s3 = l0.w;
    l.s4 = l1.x; l.s5 = l1.y; l.s6 = l1.z; l.s7 = l1.w;
}

// ----------------------------------------------------------- pool (+prep) ---
// grid 1028 = 257 docs x 4 slices, 256 thr. Each block redundantly compacts
// + bitonic-sorts its doc's active ids in LDS (deterministic), then pools a
// 1024-col slice with 8 gather rows in flight. Sorted ascending order =>
// concurrent doc-blocks sweep embed together (LLC reuse of duplicate rows).
// Sum-reorder numerically safe (scores saturate; fp32 assoc noise << thresh).
__global__ __launch_bounds__(256) void pool_kernel(
        const int* __restrict__ ids, const int* __restrict__ mask,
        const int* __restrict__ qids, const int* __restrict__ qmask,
        const float* __restrict__ embed, float* __restrict__ Pooled) {
    __shared__ int s_key[256];
    __shared__ int wofs[4];
    int bid = blockIdx.x, t = threadIdx.x;
    int doc = bid >> 2, slice = bid & 3;
    const int* I = (doc < BB) ? ids  + doc * SS : qids;
    const int* M = (doc < BB) ? mask + doc * SS : qmask;
    int id = I[t], m = M[t];
    u64 bal = __ballot(m != 0);
    int lane = t & 63, w = t >> 6;
    if (lane == 0) wofs[w] = __popcll(bal);
    s_key[t] = 0x7FFFFFFF;
    __syncthreads();
    int off = 0;
    #pragma unroll
    for (int i = 0; i < 4; ++i) if (i < w) off += wofs[i];
    int total = wofs[0] + wofs[1] + wofs[2] + wofs[3];
    if (m) s_key[off + __popcll(bal & ((1ull << lane) - 1ull))] = id;
    __syncthreads();
    // bitonic sort ascending, n=256, one element per thread
    for (int k = 2; k <= 256; k <<= 1) {
        for (int j = k >> 1; j > 0; j >>= 1) {
            int p = t ^ j;
            int a = s_key[t], c = s_key[p];
            bool dir = ((t & k) == 0);
            bool keepMin = ((t < p) == dir);
            int nv = keepMin ? (a < c ? a : c) : (a > c ? a : c);
            __syncthreads();
            s_key[t] = nv;
            __syncthreads();
        }
    }
    if (t < total) s_key[t] *= DD;       // element offsets
    else s_key[t] = 0;
    __syncthreads();

    float inv = 1.0f / ((float)total + 1e-9f);
    int col = (slice << 10) + (t << 2);
    const float* eb = embed + col;
    float ax = 0.f, ay = 0.f, az = 0.f, aw = 0.f;
    int j = 0;
    for (; j + 8 <= total; j += 8) {     // 8 independent 16B gathers in flight
        const float4 r0 = *(const float4*)(eb + s_key[j + 0]);
        const float4 r1 = *(const float4*)(eb + s_key[j + 1]);
        const float4 r2 = *(const float4*)(eb + s_key[j + 2]);
        const float4 r3 = *(const float4*)(eb + s_key[j + 3]);
        const float4 r4 = *(const float4*)(eb + s_key[j + 4]);
        const float4 r5 = *(const float4*)(eb + s_key[j + 5]);
        const float4 r6 = *(const float4*)(eb + s_key[j + 6]);
        const float4 r7 = *(const float4*)(eb + s_key[j + 7]);
        ax += ((r0.x + r1.x) + (r2.x + r3.x)) + ((r4.x + r5.x) + (r6.x + r7.x));
        ay += ((r0.y + r1.y) + (r2.y + r3.y)) + ((r4.y + r5.y) + (r6.y + r7.y));
        az += ((r0.z + r1.z) + (r2.z + r3.z)) + ((r4.z + r5.z) + (r6.z + r7.z));
        aw += ((r0.w + r1.w) + (r2.w + r3.w)) + ((r4.w + r5.w) + (r6.w + r7.w));
    }
    for (; j < total; ++j) {
        const float4 r0 = *(const float4*)(eb + s_key[j]);
        ax += r0.x; ay += r0.y; az += r0.z; aw += r0.w;
    }
    *(float4*)(Pooled + (size_t)doc * DD + col) =
        make_float4(ax * inv, ay * inv, az * inv, aw * inv);
}

// -------------------------------------------------------------- LN+split ----
// 257 blocks x 256 thr: LayerNorm Pooled row; docs -> split bf16 Xh/Xl,
// query (b==256) -> fp32 Xq.
__global__ __launch_bounds__(256) void ln_split_kernel(
        const float* __restrict__ Pooled, const float* __restrict__ g,
        const float* __restrict__ bb, short* __restrict__ Xh,
        short* __restrict__ Xl, float* __restrict__ Xq) {
    __shared__ float lds4[4];
    int b = blockIdx.x, t = threadIdx.x;
    const float* row = Pooled + (size_t)b * DD;
    float4 v[4];
    float s = 0.f;
    #pragma unroll
    for (int i = 0; i < 4; ++i) {
        v[i] = *(const float4*)(row + (t << 2) + (i << 10));
        s += (v[i].x + v[i].y) + (v[i].z + v[i].w);
    }
    #pragma unroll
    for (int o = 32; o; o >>= 1) s += __shfl_down(s, o);
    int lane = t & 63, w = t >> 6;
    if (lane == 0) lds4[w] = s;
    __syncthreads();
    float mu = (lds4[0] + lds4[1] + lds4[2] + lds4[3]) * (1.0f / DD);
    float q = 0.f;
    #pragma unroll
    for (int i = 0; i < 4; ++i) {
        float dx = v[i].x - mu, dy = v[i].y - mu, dz = v[i].z - mu, dw = v[i].w - mu;
        q += (dx * dx + dy * dy) + (dz * dz + dw * dw);
    }
    __syncthreads();
    #pragma unroll
    for (int o = 32; o; o >>= 1) q += __shfl_down(q, o);
    if (lane == 0) lds4[w] = q;
    __syncthreads();
    float var = (lds4[0] + lds4[1] + lds4[2] + lds4[3]) * (1.0f / DD);
    float sc = 1.0f / sqrtf(var + 1e-5f);
    #pragma unroll
    for (int i = 0; i < 4; ++i) {
        int col = (t << 2) + (i << 10);
        float4 gg = *(const float4*)(g + col);
        float4 bv = *(const float4*)(bb + col);
        float4 o4;
        o4.x = (v[i].x - mu) * sc * gg.x + bv.x;
        o4.y = (v[i].y - mu) * sc * gg.y + bv.y;
        o4.z = (v[i].z - mu) * sc * gg.z + bv.z;
        o4.w = (v[i].w - mu) * sc * gg.w + bv.w;
        if (b < BB) {
            sv4 h, l; split4(o4, h, l);
            *(sv4*)(Xh + (size_t)b * DD + col) = h;
            *(sv4*)(Xl + (size_t)b * DD + col) = l;
        } else {
            *(float4*)(Xq + col) = o4;
        }
    }
}

// ------------------------------------------------- split-bf16 MFMA GEMM -----
// BM=BN=128, BK=32, 256 thr (4 waves 2x2), wave tile 64x64 = 4x4 16x16 frags.
// C = Ah*Bh + Ah*Bl + Al*Bh (fp32 acc); B = fp32 weights split in-staging.
// C/D layout (m89): col = lane&15, row = (lane>>4)*4 + reg.
template <bool CONTRIB>
__device__ void gemm_mfma(
        const short* __restrict__ Ah, const short* __restrict__ Al,
        const float* __restrict__ Wf,
        int ldK, int m0, int n0, int kBase, int Kc, int N,
        float* __restrict__ Pout,
        const float* __restrict__ Qv, float* __restrict__ Contrib, int slot) {
    __shared__ short sAh[128 * 40] __attribute__((aligned(16)));
    __shared__ short sAl[128 * 40] __attribute__((aligned(16)));
    __shared__ short sBh[128 * 40] __attribute__((aligned(16)));
    __shared__ short sBl[128 * 40] __attribute__((aligned(16)));
    int tid = threadIdx.x;
    int lane = tid & 63, wv = tid >> 6;
    int wr = wv >> 1, wc = wv & 1;
    int l15 = lane & 15, grp = lane >> 4, lk = grp << 3;
    int srow = tid >> 1, soff = (tid & 1) << 4;   // 2 thr/row, 16 elems each
    f32x4 zero = {0.f, 0.f, 0.f, 0.f};
    f32x4 acc[4][4];
    #pragma unroll
    for (int i = 0; i < 4; ++i)
        #pragma unroll
        for (int j = 0; j < 4; ++j) acc[i][j] = zero;

    for (int k0 = 0; k0 < Kc; k0 += 32) {
        int gk = kBase + k0;
        size_t ga = (size_t)(m0 + srow) * ldK + gk + soff;
        sv8 vah0 = *(const sv8*)(Ah + ga);
        sv8 vah1 = *(const sv8*)(Ah + ga + 8);
        sv8 val0 = *(const sv8*)(Al + ga);
        sv8 val1 = *(const sv8*)(Al + ga + 8);
        const float* wp = Wf + (size_t)(n0 + srow) * ldK + gk + soff;
        float4 w0 = *(const float4*)(wp);
        float4 w1 = *(const float4*)(wp + 4);
        float4 w2 = *(const float4*)(wp + 8);
        float4 w3 = *(const float4*)(wp + 12);
        sv8 bh0, bl0, bh1, bl1;
        split8(w0, w1, bh0, bl0);
        split8(w2, w3, bh1, bl1);
        __syncthreads();
        int so = srow * 40 + soff;
        *(sv8*)(sAh + so) = vah0; *(sv8*)(sAh + so + 8) = vah1;
        *(sv8*)(sAl + so) = val0; *(sv8*)(sAl + so + 8) = val1;
        *(sv8*)(sBh + so) = bh0;  *(sv8*)(sBh + so + 8) = bh1;
        *(sv8*)(sBl + so) = bl0;  *(sv8*)(sBl + so + 8) = bl1;
        __syncthreads();
        sv8 fah[4], fal[4], fbh[4], fbl[4];
        #pragma unroll
        for (int i = 0; i < 4; ++i) {
            int ra = (wr * 64 + i * 16 + l15) * 40 + lk;
            int rb = (wc * 64 + i * 16 + l15) * 40 + lk;
            fah[i] = *(const sv8*)(sAh + ra);
            fal[i] = *(const sv8*)(sAl + ra);
            fbh[i] = *(const sv8*)(sBh + rb);
            fbl[i] = *(const sv8*)(sBl + rb);
        }
        #pragma unroll
        for (int i = 0; i < 4; ++i)
            #pragma unroll
            for (int j = 0; j < 4; ++j) {
                acc[i][j] = __builtin_amdgcn_mfma_f32_16x16x32_bf16(fah[i], fbh[j], acc[i][j], 0, 0, 0);
                acc[i][j] = __builtin_amdgcn_mfma_f32_16x16x32_bf16(fah[i], fbl[j], acc[i][j], 0, 0, 0);
                acc[i][j] = __builtin_amdgcn_mfma_f32_16x16x32_bf16(fal[i], fbh[j], acc[i][j], 0, 0, 0);
            }
    }

    if (CONTRIB) {
        float qv[4];
        #pragma unroll
        for (int j = 0; j < 4; ++j) qv[j] = Qv[n0 + wc * 64 + j * 16 + l15];
        #pragma unroll
        for (int i = 0; i < 4; ++i)
            #pragma unroll
            for (int r = 0; r < 4; ++r) {
                float s = acc[i][0][r] * qv[0] + acc[i][1][r] * qv[1]
                        + acc[i][2][r] * qv[2] + acc[i][3][r] * qv[3];
                s += __shfl_xor(s, 1); s += __shfl_xor(s, 2);
                s += __shfl_xor(s, 4); s += __shfl_xor(s, 8);
                if (l15 == 0) {
                    int row = m0 + wr * 64 + i * 16 + grp * 4 + r;
                    Contrib[(size_t)row * 256 + slot * 2 + wc] = s;
                }
            }
    } else {
        #pragma unroll
        for (int i = 0; i < 4; ++i)
            #pragma unroll
            for (int r = 0; r < 4; ++r) {
                int row = m0 + wr * 64 + i * 16 + grp * 4 + r;
                #pragma unroll
                for (int j = 0; j < 4; ++j)
                    Pout[(size_t)row * N + n0 + wc * 64 + j * 16 + l15] = acc[i][j][r];
            }
    }
}

// --------------------------------------------------------------- layer 1 ----
// bid<256: split-K=16 MFMA GEMM X @ kW1^T -> P1[z] (Kc=256);
// bid in [256,512): query GEMV1 (4 rows each).
__global__ __launch_bounds__(256) void layer1_kernel(
        const short* __restrict__ Xh, const short* __restrict__ Xl,
        const float* __restrict__ kW1,
        float* __restrict__ P1, const float* __restrict__ Xq,
        const float* __restrict__ qW1, const float* __restrict__ qb1,
        float* __restrict__ H1q) {
    int bid = blockIdx.x;
    if (bid < 256) {
        int z = bid & 15, nb = (bid >> 4) & 7, mb = bid >> 7;
        gemm_mfma<false>(Xh, Xl, kW1, DD, mb * 128, nb * 128, z * 256, 256,
                         HH, P1 + (size_t)z * BB * HH, nullptr, nullptr, 0);
    } else {
        int i = bid - 256, wv = threadIdx.x >> 6, lane = threadIdx.x & 63;
        int n = (i << 2) + wv;
        const float* wrow = qW1 + (size_t)n * DD;
        float s = 0.f;
        #pragma unroll
        for (int jj = 0; jj < 16; ++jj) {
            int k = jj * 256 + (lane << 2);
            float4 a = *(const float4*)(Xq + k);
            float4 ww = *(const float4*)(wrow + k);
            s += (a.x * ww.x + a.y * ww.y) + (a.z * ww.z + a.w * ww.w);
        }
        #pragma unroll
        for (int o = 32; o; o >>= 1) s += __shfl_down(s, o);
        if (lane == 0) H1q[n] = fmaxf(s + qb1[n], 0.f);
    }
}

// ------------------------------------------------------ reduce1 + GEMV2 -----
// bid<256: H1[row] = relu(sum_z P1z + kb1) -> split bf16; bid>=256: Qv GEMV.
__global__ __launch_bounds__(256) void reduce1_kernel(
        const float* __restrict__ P1, const float* __restrict__ kb1,
        short* __restrict__ H1h, short* __restrict__ H1l,
        const float* __restrict__ H1q, const float* __restrict__ qW2,
        const float* __restrict__ qb2, float* __restrict__ Qv) {
    int bid = blockIdx.x, t = threadIdx.x;
    if (bid < 256) {
        int col = t << 2;
        const float* base = P1 + (size_t)bid * HH + col;
        float4 s = *(const float4*)(kb1 + col);
        #pragma unroll
        for (int z = 0; z < 16; ++z) {
            float4 p = *(const float4*)(base + (size_t)z * BB * HH);
            s.x += p.x; s.y += p.y; s.z += p.z; s.w += p.w;
        }
        s.x = fmaxf(s.x, 0.f); s.y = fmaxf(s.y, 0.f);
        s.z = fmaxf(s.z, 0.f); s.w = fmaxf(s.w, 0.f);
        sv4 h, l; split4(s, h, l);
        size_t o = (size_t)bid * HH + col;
        *(sv4*)(H1h + o) = h;
        *(sv4*)(H1l + o) = l;
    } else {
        int i = bid - 256, wv = t >> 6, lane = t & 63;
        int n = (i << 2) + wv;
        const float* wrow = qW2 + (size_t)n * HH;
        float s = 0.f;
        #pragma unroll
        for (int jj = 0; jj < 4; ++jj) {
            int k = jj * 256 + (lane << 2);
            float4 a = *(const float4*)(H1q + k);
            float4 ww = *(const float4*)(wrow + k);
            s += (a.x * ww.x + a.y * ww.y) + (a.z * ww.z + a.w * ww.w);
        }
        #pragma unroll
        for (int o = 32; o; o >>= 1) s += __shfl_down(s, o);
        if (lane == 0) Qv[n] = s + qb2[n];
    }
}

// --------------------------------------------------------------- layer 2 ----
// split-K=16 MFMA GEMM H1 @ kW2^T, tile reduced against Qv -> Contrib.
__global__ __launch_bounds__(256) void layer2_kernel(
        const short* __restrict__ H1h, const short* __restrict__ H1l,
        const float* __restrict__ kW2,
        const float* __restrict__ Qv, float* __restrict__ Contrib) {
    int bid = blockIdx.x;
    int z = bid & 15, nb = (bid >> 4) & 7, mb = bid >> 7;
    gemm_mfma<true>(H1h, H1l, kW2, HH, mb * 128, nb * 128, z * 64, 64,
                    HH, nullptr, Qv, Contrib, z * 8 + nb);
}

// ------------------------------------------------- final: scores + topk -----
__global__ __launch_bounds__(1024) void final_kernel(
        const float* __restrict__ Contrib, const float* __restrict__ kb2,
        const float* __restrict__ Qv, const int* __restrict__ kptr,
        float* __restrict__ out) {
    __shared__ float red[16];
    __shared__ float ss[BB];
    __shared__ float rv[16];
    __shared__ int   ri[16];
    __shared__ float s_bq;
    int t = threadIdx.x, lane = t & 63, w = t >> 6;
    float v = kb2[t] * Qv[t];
    #pragma unroll
    for (int o = 32; o; o >>= 1) v += __shfl_down(v, o);
    if (lane == 0) red[w] = v;
    __syncthreads();
    if (t == 0) {
        float b = 0.f;
        #pragma unroll
        for (int i = 0; i < 16; ++i) b += red[i];
        s_bq = b;
    }
    __syncthreads();
    if (t < BB) {
        const float* c = Contrib + (size_t)t * 256;
        float sx = 0.f, sy = 0.f, sz = 0.f, sw = 0.f;
        for (int j = 0; j < 256; j += 4) {
            float4 e = *(const float4*)(c + j);
            sx += e.x; sy += e.y; sz += e.z; sw += e.w;
        }
        float lg = s_bq + ((sx + sy) + (sz + sw));
        ss[t] = 1.0f / (1.0f + expf(-lg));
    }
    __syncthreads();
    int k = kptr[0];
    if (k > BB) k = BB;
    for (int i = 0; i < k; ++i) {
        float vv = (t < BB) ? ss[t] : -3.3e38f;
        int vi = t;
        #pragma unroll
        for (int o = 32; o; o >>= 1) {
            float ov = __shfl_down(vv, o);
            int   oi = __shfl_down(vi, o);
            if (ov > vv || (ov == vv && oi < vi)) { vv = ov; vi = oi; }
        }
        if (lane == 0) { rv[w] = vv; ri[w] = vi; }
        __syncthreads();
        if (t == 0) {
            float bv = rv[0]; int bi = ri[0];
            #pragma unroll
            for (int j = 1; j < 16; ++j)
                if (rv[j] > bv || (rv[j] == bv && ri[j] < bi)) { bv = rv[j]; bi = ri[j]; }
            out[i]     = bv;
            out[k + i] = (float)bi;
            ss[bi] = -3.0e38f;
        }
        __syncthreads();
    }
}

// ---------------------------------------------------------------- launch ----
extern "C" void kernel_launch(void* const* d_in, const int* in_sizes, int n_in,
                              void* d_out, int out_size, void* d_ws, size_t ws_size,
                              hipStream_t stream) {
    const int*   input_ids  = (const int*)d_in[0];
    const int*   attn_mask  = (const int*)d_in[1];
    const int*   query_ids  = (const int*)d_in[2];
    const int*   query_mask = (const int*)d_in[3];
    const float* embed      = (const float*)d_in[4];
    const float* ln_g       = (const float*)d_in[5];
    const float* ln_b       = (const float*)d_in[6];
    const float* kW1        = (const float*)d_in[7];
    const float* kb1        = (const float*)d_in[8];
    const float* kW2        = (const float*)d_in[9];
    const float* kb2        = (const float*)d_in[10];
    const float* qW1        = (const float*)d_in[11];
    const float* qb1        = (const float*)d_in[12];
    const float* qW2        = (const float*)d_in[13];
    const float* qb2        = (const float*)d_in[14];
    const int*   kptr       = (const int*)d_in[15];

    char* p = (char*)d_ws;
    auto carve = [&](size_t bytes) {
        char* r = p;
        p += (bytes + 255) & ~(size_t)255;
        return r;
    };
    float* Pooled    = (float*)carve((size_t)257 * DD * 4);
    float* Xq        = (float*)carve((size_t)DD * 4);
    short* Xh        = (short*)carve((size_t)BB * DD * 2);
    short* Xl        = (short*)carve((size_t)BB * DD * 2);
    float* P1        = (float*)carve((size_t)16 * BB * HH * 4);
    float* H1q       = (float*)carve((size_t)HH * 4);
    short* H1h       = (short*)carve((size_t)BB * HH * 2);
    short* H1l      = (short*)carve((size_t)BB * HH * 2);
    float* Qv        = (float*)carve((size_t)HH * 4);
    float* Contrib   = (float*)carve((size_t)BB * 256 * 4);

    pool_kernel<<<1028, 256, 0, stream>>>(input_ids, attn_mask, query_ids,
                                          query_mask, embed, Pooled);
    ln_split_kernel<<<257, 256, 0, stream>>>(Pooled, ln_g, ln_b, Xh, Xl, Xq);
    layer1_kernel<<<512, 256, 0, stream>>>(Xh, Xl, kW1, P1, Xq, qW1, qb1, H1q);
    reduce1_kernel<<<512, 256, 0, stream>>>(P1, kb1, H1h, H1l, H1q, qW2, qb2, Qv);
    layer2_kernel<<<256, 256, 0, stream>>>(H1h, H1l, kW2, Qv, Contrib);
    final_kernel<<<1, 1024, 0, stream>>>(Contrib, kb2, Qv, kptr, (float*)d_out);
}

// Round 11
// 136.724 us; speedup vs baseline: 1.1026x; 1.0841x over previous
//
#include <hip/hip_runtime.h>
#include <math.h>

#define DD 4096
#define HH 1024
#define BB 256
#define SS 256

typedef unsigned long long u64;
typedef __attribute__((ext_vector_type(4))) short sv4;
typedef __attribute__((ext_vector_type(8))) short sv8;
typedef __attribute__((ext_vector_type(4))) float f32x4;

// ------------------------------------------------------------ bf16 split ----
__device__ __forceinline__ unsigned short f2bf(float x) {
    union { float f; unsigned u; } c; c.f = x;
    unsigned r = c.u + 0x7FFFu + ((c.u >> 16) & 1u);
    return (unsigned short)(r >> 16);
}
__device__ __forceinline__ float bf2f(unsigned short h) {
    union { unsigned u; float f; } c; c.u = ((unsigned)h) << 16;
    return c.f;
}
// x = hi + lo with hi,lo bf16 (RNE twice) -> ~2^-16 relative residual
__device__ __forceinline__ void split4(const float4& v, sv4& h, sv4& l) {
    unsigned short hx = f2bf(v.x), hy = f2bf(v.y), hz = f2bf(v.z), hw = f2bf(v.w);
    h.x = (short)hx; h.y = (short)hy; h.z = (short)hz; h.w = (short)hw;
    l.x = (short)f2bf(v.x - bf2f(hx)); l.y = (short)f2bf(v.y - bf2f(hy));
    l.z = (short)f2bf(v.z - bf2f(hz)); l.w = (short)f2bf(v.w - bf2f(hw));
}
// two float4 (16 consecutive floats) -> sv8 hi + sv8 lo
__device__ __forceinline__ void split8(const float4& a, const float4& b,
                                       sv8& h, sv8& l) {
    sv4 h0, l0, h1, l1;
    split4(a, h0, l0);
    split4(b, h1, l1);
    h.s0 = h0.x; h.s1 = h0.y; h.s2 = h0.z; h.s3 = h0.w;
    h.s4 = h1.x; h.s5 = h1.y; h.s6 = h1.z; h.s7 = h1.w;
    l.s0 = l0.x; l.s1 = l0.y; l.s2 = l0.z; l.s3 = l0.w;
    l.s4 = l1.x; l.s5 = l1.y; l.s6 = l1.z; l.s7 = l1.w;
}

// ------------------------------------------------------------------ prep ----
// 257 blocks x 256 thr (R7-verbatim). Compact active ids, bitonic-sort
// ascending, write SortedOff[b][i] = id*DD and Count[b].
__global__ __launch_bounds__(256) void prep_kernel(
        const int* __restrict__ ids, const int* __restrict__ mask,
        const int* __restrict__ qids, const int* __restrict__ qmask,
        int* __restrict__ SortedOff, int* __restrict__ Count) {
    __shared__ int s_key[256];
    __shared__ int wofs[4];
    int b = blockIdx.x, t = threadIdx.x;
    const int* I = (b < BB) ? ids  + b * SS : qids;
    const int* M = (b < BB) ? mask + b * SS : qmask;
    int id = I[t], m = M[t];
    u64 bal = __ballot(m != 0);
    int lane = t & 63, w = t >> 6;
    if (lane == 0) wofs[w] = __popcll(bal);
    s_key[t] = 0x7FFFFFFF;
    __syncthreads();
    int off = 0;
    #pragma unroll
    for (int i = 0; i < 4; ++i) if (i < w) off += wofs[i];
    int total = wofs[0] + wofs[1] + wofs[2] + wofs[3];
    if (m) s_key[off + __popcll(bal & ((1ull << lane) - 1ull))] = id;
    __syncthreads();
    for (int k = 2; k <= 256; k <<= 1) {
        for (int j = k >> 1; j > 0; j >>= 1) {
            int p = t ^ j;
            int a = s_key[t], c = s_key[p];
            bool dir = ((t & k) == 0);
            bool keepMin = ((t < p) == dir);
            int nv = keepMin ? (a < c ? a : c) : (a > c ? a : c);
            __syncthreads();
            s_key[t] = nv;
            __syncthreads();
        }
    }
    SortedOff[b * 256 + t] = (t < total) ? s_key[t] * DD : 0;
    if (t == 0) Count[b] = total;
}

// ------------------------------------------------------------------ pool ----
// R7-verbatim (4112 = 257 docs x 16 slices, 64 thr, 8-deep gather) + per-slice
// LN partial sums S1/S2 (one wave-reduce, 2 stores).
__global__ __launch_bounds__(64) void pool_kernel(
        const int* __restrict__ SortedOff, const int* __restrict__ Count,
        const float* __restrict__ embed, float* __restrict__ Pooled,
        float* __restrict__ S1, float* __restrict__ S2) {
    __shared__ int s_off[256];
    int bid = blockIdx.x, t = threadIdx.x;
    int doc = bid >> 4, slice = bid & 15;
    int total = Count[doc];
    #pragma unroll
    for (int i = 0; i < 4; ++i) s_off[t + i * 64] = SortedOff[doc * 256 + t + i * 64];
    __syncthreads();
    float inv = 1.0f / ((float)total + 1e-9f);
    int col = (slice << 8) + (t << 2);
    const float* eb = embed + col;
    float ax = 0.f, ay = 0.f, az = 0.f, aw = 0.f;
    int j = 0;
    for (; j + 8 <= total; j += 8) {
        const float4 r0 = *(const float4*)(eb + s_off[j + 0]);
        const float4 r1 = *(const float4*)(eb + s_off[j + 1]);
        const float4 r2 = *(const float4*)(eb + s_off[j + 2]);
        const float4 r3 = *(const float4*)(eb + s_off[j + 3]);
        const float4 r4 = *(const float4*)(eb + s_off[j + 4]);
        const float4 r5 = *(const float4*)(eb + s_off[j + 5]);
        const float4 r6 = *(const float4*)(eb + s_off[j + 6]);
        const float4 r7 = *(const float4*)(eb + s_off[j + 7]);
        ax += ((r0.x + r1.x) + (r2.x + r3.x)) + ((r4.x + r5.x) + (r6.x + r7.x));
        ay += ((r0.y + r1.y) + (r2.y + r3.y)) + ((r4.y + r5.y) + (r6.y + r7.y));
        az += ((r0.z + r1.z) + (r2.z + r3.z)) + ((r4.z + r5.z) + (r6.z + r7.z));
        aw += ((r0.w + r1.w) + (r2.w + r3.w)) + ((r4.w + r5.w) + (r6.w + r7.w));
    }
    for (; j < total; ++j) {
        const float4 r0 = *(const float4*)(eb + s_off[j]);
        ax += r0.x; ay += r0.y; az += r0.z; aw += r0.w;
    }
    float4 res = make_float4(ax * inv, ay * inv, az * inv, aw * inv);
    *(float4*)(Pooled + (size_t)doc * DD + col) = res;
    float s1 = (res.x + res.y) + (res.z + res.w);
    float s2 = (res.x * res.x + res.y * res.y) + (res.z * res.z + res.w * res.w);
    #pragma unroll
    for (int o = 32; o; o >>= 1) {
        s1 += __shfl_down(s1, o);
        s2 += __shfl_down(s2, o);
    }
    if (t == 0) {
        S1[doc * 16 + slice] = s1;
        S2[doc * 16 + slice] = s2;
    }
}

// ------------------------------------------------- split-bf16 MFMA GEMM -----
// BM=BN=128, BK=32, 256 thr (4 waves 2x2), wave tile 64x64 = 4x4 16x16 frags.
// C = Ah*Bh + Ah*Bl + Al*Bh (fp32 acc); B = fp32 weights split in-staging.
// C/D layout (m89): col = lane&15, row = (lane>>4)*4 + reg.
// LN_A: A(m,k) = ((Pooled[m][k]-mu[m])*sc[m]*g[k]+b[k]) split in-staging;
//       mu/sc from 16 per-slice partials (E[x^2]-mu^2; no cancellation here).
// CONTRIB: reduce tile rows against Qv into Contrib[row][slot*2+wc].
template <bool LN_A, bool CONTRIB>
__device__ void gemm_mfma(
        short* sAh, short* sAl, short* sBh, short* sBl,
        float* muS, float* scS, float* sg, float* sb,
        const float* __restrict__ Af,
        const short* __restrict__ Ah, const short* __restrict__ Al,
        const float* __restrict__ S1, const float* __restrict__ S2,
        const float* __restrict__ ln_g, const float* __restrict__ ln_b,
        const float* __restrict__ Wf,
        int ldK, int m0, int n0, int kBase, int Kc, int N,
        float* __restrict__ Pout,
        const float* __restrict__ Qv, float* __restrict__ Contrib, int slot) {
    int tid = threadIdx.x;
    int lane = tid & 63, wv = tid >> 6;
    int wr = wv >> 1, wc = wv & 1;
    int l15 = lane & 15, grp = lane >> 4, lk = grp << 3;
    int srow = tid >> 1, soff = (tid & 1) << 4;   // 2 thr/row, 16 elems each
    f32x4 zero = {0.f, 0.f, 0.f, 0.f};
    f32x4 acc[4][4];
    #pragma unroll
    for (int i = 0; i < 4; ++i)
        #pragma unroll
        for (int j = 0; j < 4; ++j) acc[i][j] = zero;

    if (LN_A) {
        if (tid < 128) {
            int row = m0 + tid;
            float a1 = 0.f, a2 = 0.f;
            #pragma unroll
            for (int s = 0; s < 16; ++s) {
                a1 += S1[row * 16 + s];
                a2 += S2[row * 16 + s];
            }
            float mu = a1 * (1.0f / DD);
            float var = a2 * (1.0f / DD) - mu * mu;
            muS[tid] = mu;
            scS[tid] = 1.0f / sqrtf(var + 1e-5f);
        }
        for (int i = tid; i < Kc; i += 256) {
            sg[i] = ln_g[kBase + i];
            sb[i] = ln_b[kBase + i];
        }
        __syncthreads();
    }

    for (int k0 = 0; k0 < Kc; k0 += 32) {
        int gk = kBase + k0;
        sv8 vah0, vah1, val0, val1;
        if (LN_A) {
            size_t ga = (size_t)(m0 + srow) * ldK + gk + soff;
            float4 p0 = *(const float4*)(Af + ga);
            float4 p1 = *(const float4*)(Af + ga + 4);
            float4 p2 = *(const float4*)(Af + ga + 8);
            float4 p3 = *(const float4*)(Af + ga + 12);
            float mu = muS[srow], scv = scS[srow];
            int lkk = k0 + soff;
            float4 g0 = *(const float4*)(sg + lkk);
            float4 g1 = *(const float4*)(sg + lkk + 4);
            float4 g2 = *(const float4*)(sg + lkk + 8);
            float4 g3 = *(const float4*)(sg + lkk + 12);
            float4 b0 = *(const float4*)(sb + lkk);
            float4 b1 = *(const float4*)(sb + lkk + 4);
            float4 b2 = *(const float4*)(sb + lkk + 8);
            float4 b3 = *(const float4*)(sb + lkk + 12);
            float4 o0, o1, o2, o3;
            o0.x = (p0.x - mu) * scv * g0.x + b0.x;
            o0.y = (p0.y - mu) * scv * g0.y + b0.y;
            o0.z = (p0.z - mu) * scv * g0.z + b0.z;
            o0.w = (p0.w - mu) * scv * g0.w + b0.w;
            o1.x = (p1.x - mu) * scv * g1.x + b1.x;
            o1.y = (p1.y - mu) * scv * g1.y + b1.y;
            o1.z = (p1.z - mu) * scv * g1.z + b1.z;
            o1.w = (p1.w - mu) * scv * g1.w + b1.w;
            o2.x = (p2.x - mu) * scv * g2.x + b2.x;
            o2.y = (p2.y - mu) * scv * g2.y + b2.y;
            o2.z = (p2.z - mu) * scv * g2.z + b2.z;
            o2.w = (p2.w - mu) * scv * g2.w + b2.w;
            o3.x = (p3.x - mu) * scv * g3.x + b3.x;
            o3.y = (p3.y - mu) * scv * g3.y + b3.y;
            o3.z = (p3.z - mu) * scv * g3.z + b3.z;
            o3.w = (p3.w - mu) * scv * g3.w + b3.w;
            split8(o0, o1, vah0, val0);
            split8(o2, o3, vah1, val1);
        } else {
            size_t ga = (size_t)(m0 + srow) * ldK + gk + soff;
            vah0 = *(const sv8*)(Ah + ga);
            vah1 = *(const sv8*)(Ah + ga + 8);
            val0 = *(const sv8*)(Al + ga);
            val1 = *(const sv8*)(Al + ga + 8);
        }
        const float* wp = Wf + (size_t)(n0 + srow) * ldK + gk + soff;
        float4 w0 = *(const float4*)(wp);
        float4 w1 = *(const float4*)(wp + 4);
        float4 w2 = *(const float4*)(wp + 8);
        float4 w3 = *(const float4*)(wp + 12);
        sv8 bh0, bl0, bh1, bl1;
        split8(w0, w1, bh0, bl0);
        split8(w2, w3, bh1, bl1);
        __syncthreads();                 // prior iter's frag reads done
        int so = srow * 40 + soff;
        *(sv8*)(sAh + so) = vah0; *(sv8*)(sAh + so + 8) = vah1;
        *(sv8*)(sAl + so) = val0; *(sv8*)(sAl + so + 8) = val1;
        *(sv8*)(sBh + so) = bh0;  *(sv8*)(sBh + so + 8) = bh1;
        *(sv8*)(sBl + so) = bl0;  *(sv8*)(sBl + so + 8) = bl1;
        __syncthreads();
        sv8 fah[4], fal[4], fbh[4], fbl[4];
        #pragma unroll
        for (int i = 0; i < 4; ++i) {
            int ra = (wr * 64 + i * 16 + l15) * 40 + lk;
            int rb = (wc * 64 + i * 16 + l15) * 40 + lk;
            fah[i] = *(const sv8*)(sAh + ra);
            fal[i] = *(const sv8*)(sAl + ra);
            fbh[i] = *(const sv8*)(sBh + rb);
            fbl[i] = *(const sv8*)(sBl + rb);
        }
        #pragma unroll
        for (int i = 0; i < 4; ++i)
            #pragma unroll
            for (int j = 0; j < 4; ++j) {
                acc[i][j] = __builtin_amdgcn_mfma_f32_16x16x32_bf16(fah[i], fbh[j], acc[i][j], 0, 0, 0);
                acc[i][j] = __builtin_amdgcn_mfma_f32_16x16x32_bf16(fah[i], fbl[j], acc[i][j], 0, 0, 0);
                acc[i][j] = __builtin_amdgcn_mfma_f32_16x16x32_bf16(fal[i], fbh[j], acc[i][j], 0, 0, 0);
            }
    }

    if (CONTRIB) {
        float qv[4];
        #pragma unroll
        for (int j = 0; j < 4; ++j) qv[j] = Qv[n0 + wc * 64 + j * 16 + l15];
        #pragma unroll
        for (int i = 0; i < 4; ++i)
            #pragma unroll
            for (int r = 0; r < 4; ++r) {
                float s = acc[i][0][r] * qv[0] + acc[i][1][r] * qv[1]
                        + acc[i][2][r] * qv[2] + acc[i][3][r] * qv[3];
                s += __shfl_xor(s, 1); s += __shfl_xor(s, 2);
                s += __shfl_xor(s, 4); s += __shfl_xor(s, 8);
                if (l15 == 0) {
                    int row = m0 + wr * 64 + i * 16 + grp * 4 + r;
                    Contrib[(size_t)row * 256 + slot * 2 + wc] = s;
                }
            }
    } else {
        #pragma unroll
        for (int i = 0; i < 4; ++i)
            #pragma unroll
            for (int r = 0; r < 4; ++r) {
                int row = m0 + wr * 64 + i * 16 + grp * 4 + r;
                #pragma unroll
                for (int j = 0; j < 4; ++j)
                    Pout[(size_t)row * N + n0 + wc * 64 + j * 16 + l15] = acc[i][j][r];
            }
    }
}

// --------------------------------------------------------------- layer 1 ----
// bid<256: split-K=16 MFMA GEMM LN(Pooled) @ kW1^T -> P1[z] (Kc=256);
// bid in [256,512): query GEMV1 with LN'd query staged to LDS.
__global__ __launch_bounds__(256) void layer1_kernel(
        const float* __restrict__ Pooled,
        const float* __restrict__ S1, const float* __restrict__ S2,
        const float* __restrict__ ln_g, const float* __restrict__ ln_b,
        const float* __restrict__ kW1, float* __restrict__ P1,
        const float* __restrict__ qW1, const float* __restrict__ qb1,
        float* __restrict__ H1q) {
    __shared__ char smem[44032] __attribute__((aligned(16)));
    int bid = blockIdx.x, t = threadIdx.x;
    if (bid < 256) {
        short* sAh = (short*)smem;
        short* sAl = (short*)(smem + 10240);
        short* sBh = (short*)(smem + 20480);
        short* sBl = (short*)(smem + 30720);
        float* muS = (float*)(smem + 40960);
        float* scS = (float*)(smem + 41472);
        float* sg  = (float*)(smem + 41984);
        float* sb  = (float*)(smem + 43008);
        int z = bid & 15, nb = (bid >> 4) & 7, mb = bid >> 7;
        gemm_mfma<true, false>(sAh, sAl, sBh, sBl, muS, scS, sg, sb,
                               Pooled, nullptr, nullptr, S1, S2, ln_g, ln_b,
                               kW1, DD, mb * 128, nb * 128, z * 256, 256,
                               HH, P1 + (size_t)z * BB * HH, nullptr, nullptr, 0);
    } else {
        float* qx = (float*)smem;   // 16 KB: LN'd query row
        int i = bid - 256, wv = t >> 6, lane = t & 63;
        float a1 = 0.f, a2 = 0.f;
        #pragma unroll
        for (int s = 0; s < 16; ++s) {
            a1 += S1[BB * 16 + s];
            a2 += S2[BB * 16 + s];
        }
        float mu = a1 * (1.0f / DD);
        float sc = 1.0f / sqrtf(a2 * (1.0f / DD) - mu * mu + 1e-5f);
        const float* qrow = Pooled + (size_t)BB * DD;
        for (int k = t; k < 1024; k += 256) {
            int c = k << 2;
            float4 pv = *(const float4*)(qrow + c);
            float4 gv = *(const float4*)(ln_g + c);
            float4 bv = *(const float4*)(ln_b + c);
            float4 ov;
            ov.x = (pv.x - mu) * sc * gv.x + bv.x;
            ov.y = (pv.y - mu) * sc * gv.y + bv.y;
            ov.z = (pv.z - mu) * sc * gv.z + bv.z;
            ov.w = (pv.w - mu) * sc * gv.w + bv.w;
            *(float4*)(qx + c) = ov;
        }
        __syncthreads();
        int n = (i << 2) + wv;
        const float* wrow = qW1 + (size_t)n * DD;
        float s = 0.f;
        #pragma unroll
        for (int jj = 0; jj < 16; ++jj) {
            int k = jj * 256 + (lane << 2);
            float4 a = *(const float4*)(qx + k);
            float4 ww = *(const float4*)(wrow + k);
            s += (a.x * ww.x + a.y * ww.y) + (a.z * ww.z + a.w * ww.w);
        }
        #pragma unroll
        for (int o = 32; o; o >>= 1) s += __shfl_down(s, o);
        if (lane == 0) H1q[n] = fmaxf(s + qb1[n], 0.f);
    }
}

// ------------------------------------------------------ reduce1 + GEMV2 -----
// bid<256: H1[row] = relu(sum_z P1z + kb1) -> split bf16; bid>=256: Qv GEMV.
__global__ __launch_bounds__(256) void reduce1_kernel(
        const float* __restrict__ P1, const float* __restrict__ kb1,
        short* __restrict__ H1h, short* __restrict__ H1l,
        const float* __restrict__ H1q, const float* __restrict__ qW2,
        const float* __restrict__ qb2, float* __restrict__ Qv) {
    int bid = blockIdx.x, t = threadIdx.x;
    if (bid < 256) {
        int col = t << 2;
        const float* base = P1 + (size_t)bid * HH + col;
        float4 s = *(const float4*)(kb1 + col);
        #pragma unroll
        for (int z = 0; z < 16; ++z) {
            float4 p = *(const float4*)(base + (size_t)z * BB * HH);
            s.x += p.x; s.y += p.y; s.z += p.z; s.w += p.w;
        }
        s.x = fmaxf(s.x, 0.f); s.y = fmaxf(s.y, 0.f);
        s.z = fmaxf(s.z, 0.f); s.w = fmaxf(s.w, 0.f);
        sv4 h, l; split4(s, h, l);
        size_t o = (size_t)bid * HH + col;
        *(sv4*)(H1h + o) = h;
        *(sv4*)(H1l + o) = l;
    } else {
        int i = bid - 256, wv = t >> 6, lane = t & 63;
        int n = (i << 2) + wv;
        const float* wrow = qW2 + (size_t)n * HH;
        float s = 0.f;
        #pragma unroll
        for (int jj = 0; jj < 4; ++jj) {
            int k = jj * 256 + (lane << 2);
            float4 a = *(const float4*)(H1q + k);
            float4 ww = *(const float4*)(wrow + k);
            s += (a.x * ww.x + a.y * ww.y) + (a.z * ww.z + a.w * ww.w);
        }
        #pragma unroll
        for (int o = 32; o; o >>= 1) s += __shfl_down(s, o);
        if (lane == 0) Qv[n] = s + qb2[n];
    }
}

// --------------------------------------------------------------- layer 2 ----
// split-K=16 MFMA GEMM H1 @ kW2^T, tile reduced against Qv -> Contrib.
__global__ __launch_bounds__(256) void layer2_kernel(
        const short* __restrict__ H1h, const short* __restrict__ H1l,
        const float* __restrict__ kW2,
        const float* __restrict__ Qv, float* __restrict__ Contrib) {
    __shared__ char smem[40960] __attribute__((aligned(16)));
    short* sAh = (short*)smem;
    short* sAl = (short*)(smem + 10240);
    short* sBh = (short*)(smem + 20480);
    short* sBl = (short*)(smem + 30720);
    int bid = blockIdx.x;
    int z = bid & 15, nb = (bid >> 4) & 7, mb = bid >> 7;
    gemm_mfma<false, true>(sAh, sAl, sBh, sBl, nullptr, nullptr, nullptr, nullptr,
                           nullptr, H1h, H1l, nullptr, nullptr, nullptr, nullptr,
                           kW2, HH, mb * 128, nb * 128, z * 64, 64,
                           HH, nullptr, Qv, Contrib, z * 8 + nb);
}

// ------------------------------------------------- final: scores + topk -----
__global__ __launch_bounds__(1024) void final_kernel(
        const float* __restrict__ Contrib, const float* __restrict__ kb2,
        const float* __restrict__ Qv, const int* __restrict__ kptr,
        float* __restrict__ out) {
    __shared__ float red[16];
    __shared__ float ss[BB];
    __shared__ float rv[16];
    __shared__ int   ri[16];
    __shared__ float s_bq;
    int t = threadIdx.x, lane = t & 63, w = t >> 6;
    float v = kb2[t] * Qv[t];
    #pragma unroll
    for (int o = 32; o; o >>= 1) v += __shfl_down(v, o);
    if (lane == 0) red[w] = v;
    __syncthreads();
    if (t == 0) {
        float b = 0.f;
        #pragma unroll
        for (int i = 0; i < 16; ++i) b += red[i];
        s_bq = b;
    }
    __syncthreads();
    if (t < BB) {
        const float* c = Contrib + (size_t)t * 256;
        float sx = 0.f, sy = 0.f, sz = 0.f, sw = 0.f;
        for (int j = 0; j < 256; j += 4) {
            float4 e = *(const float4*)(c + j);
            sx += e.x; sy += e.y; sz += e.z; sw += e.w;
        }
        float lg = s_bq + ((sx + sy) + (sz + sw));
        ss[t] = 1.0f / (1.0f + expf(-lg));
    }
    __syncthreads();
    int k = kptr[0];
    if (k > BB) k = BB;
    for (int i = 0; i < k; ++i) {
        float vv = (t < BB) ? ss[t] : -3.3e38f;
        int vi = t;
        #pragma unroll
        for (int o = 32; o; o >>= 1) {
            float ov = __shfl_down(vv, o);
            int   oi = __shfl_down(vi, o);
            if (ov > vv || (ov == vv && oi < vi)) { vv = ov; vi = oi; }
        }
        if (lane == 0) { rv[w] = vv; ri[w] = vi; }
        __syncthreads();
        if (t == 0) {
            float bv = rv[0]; int bi = ri[0];
            #pragma unroll
            for (int j = 1; j < 16; ++j)
                if (rv[j] > bv || (rv[j] == bv && ri[j] < bi)) { bv = rv[j]; bi = ri[j]; }
            out[i]     = bv;
            out[k + i] = (float)bi;
            ss[bi] = -3.0e38f;
        }
        __syncthreads();
    }
}

// ---------------------------------------------------------------- launch ----
extern "C" void kernel_launch(void* const* d_in, const int* in_sizes, int n_in,
                              void* d_out, int out_size, void* d_ws, size_t ws_size,
                              hipStream_t stream) {
    const int*   input_ids  = (const int*)d_in[0];
    const int*   attn_mask  = (const int*)d_in[1];
    const int*   query_ids  = (const int*)d_in[2];
    const int*   query_mask = (const int*)d_in[3];
    const float* embed      = (const float*)d_in[4];
    const float* ln_g       = (const float*)d_in[5];
    const float* ln_b       = (const float*)d_in[6];
    const float* kW1        = (const float*)d_in[7];
    const float* kb1        = (const float*)d_in[8];
    const float* kW2        = (const float*)d_in[9];
    const float* kb2        = (const float*)d_in[10];
    const float* qW1        = (const float*)d_in[11];
    const float* qb1        = (const float*)d_in[12];
    const float* qW2        = (const float*)d_in[13];
    const float* qb2        = (const float*)d_in[14];
    const int*   kptr       = (const int*)d_in[15];

    char* p = (char*)d_ws;
    auto carve = [&](size_t bytes) {
        char* r = p;
        p += (bytes + 255) & ~(size_t)255;
        return r;
    };
    int*   SortedOff = (int*)carve((size_t)257 * 256 * 4);
    int*   Count     = (int*)carve((size_t)257 * 4);
    float* Pooled    = (float*)carve((size_t)257 * DD * 4);
    float* S1        = (float*)carve((size_t)257 * 16 * 4);
    float* S2        = (float*)carve((size_t)257 * 16 * 4);
    float* P1        = (float*)carve((size_t)16 * BB * HH * 4);
    float* H1q       = (float*)carve((size_t)HH * 4);
    short* H1h       = (short*)carve((size_t)BB * HH * 2);
    short* H1l       = (short*)carve((size_t)BB * HH * 2);
    float* Qv        = (float*)carve((size_t)HH * 4);
    float* Contrib   = (float*)carve((size_t)BB * 256 * 4);

    prep_kernel<<<257, 256, 0, stream>>>(input_ids, attn_mask, query_ids,
                                         query_mask, SortedOff, Count);
    pool_kernel<<<4112, 64, 0, stream>>>(SortedOff, Count, embed, Pooled, S1, S2);
    layer1_kernel<<<512, 256, 0, stream>>>(Pooled, S1, S2, ln_g, ln_b,
                                           kW1, P1, qW1, qb1, H1q);
    reduce1_kernel<<<512, 256, 0, stream>>>(P1, kb1, H1h, H1l, H1q, qW2, qb2, Qv);
    layer2_kernel<<<256, 256, 0, stream>>>(H1h, H1l, kW2, Qv, Contrib);
    final_kernel<<<1, 1024, 0, stream>>>(Contrib, kb2, Qv, kptr, (float*)d_out);
}